// Round 7
// baseline (62.023 us; speedup 1.0000x reference)
//
#include <hip/hip_runtime.h>
#include <hip/hip_bf16.h>

#define BETA_INV 12.5f
#define EPS_NRM 1e-8f
#define NPAIR 4096
#define DDIM 256
#define MROWS 8192   // 2N
#define NT2 32       // 8192 / 256
#define NBLK2 (NT2 * (NT2 + 1) / 2)   // 528 upper-triangle 256x256 tiles

typedef __attribute__((ext_vector_type(8))) short bf16x8;   // 8 bf16 = 4 VGPRs
typedef __attribute__((ext_vector_type(4))) float f32x4;

// ---------------------------------------------------------------------------
// Kernel 1: row-pair normalize (verified). One wave per pair.
// Also zeroes denom[] so no separate memset dispatch.
// ---------------------------------------------------------------------------
__global__ __launch_bounds__(256) void cl_normalize(
    const float* __restrict__ x1, const float* __restrict__ x2,
    ushort* __restrict__ zn, float* __restrict__ pos_half,
    float* __restrict__ denom) {
  if (blockIdx.x < 32) denom[blockIdx.x * 256 + threadIdx.x] = 0.0f;

  int wid  = threadIdx.x >> 6;
  int lane = threadIdx.x & 63;
  int row  = blockIdx.x * 4 + wid;           // pair index in [0, 4096)
  const float4* p1 = (const float4*)(x1 + row * DDIM);
  const float4* p2 = (const float4*)(x2 + row * DDIM);
  float4 a = p1[lane];
  float4 b = p2[lane];
  float s11 = a.x*a.x + a.y*a.y + a.z*a.z + a.w*a.w;
  float s22 = b.x*b.x + b.y*b.y + b.z*b.z + b.w*b.w;
  float s12 = a.x*b.x + a.y*b.y + a.z*b.z + a.w*b.w;
  #pragma unroll
  for (int m = 1; m < 64; m <<= 1) {
    s11 += __shfl_xor(s11, m);
    s22 += __shfl_xor(s22, m);
    s12 += __shfl_xor(s12, m);
  }
  float r1 = fmaxf(sqrtf(s11), EPS_NRM);
  float r2 = fmaxf(sqrtf(s22), EPS_NRM);
  float i1 = 1.0f / r1, i2 = 1.0f / r2;

  union { ushort4 u; __hip_bfloat16 h[4]; } w1, w2;
  w1.h[0] = __float2bfloat16(a.x * i1); w1.h[1] = __float2bfloat16(a.y * i1);
  w1.h[2] = __float2bfloat16(a.z * i1); w1.h[3] = __float2bfloat16(a.w * i1);
  w2.h[0] = __float2bfloat16(b.x * i2); w2.h[1] = __float2bfloat16(b.y * i2);
  w2.h[2] = __float2bfloat16(b.z * i2); w2.h[3] = __float2bfloat16(b.w * i2);
  *(ushort4*)(zn + row * DDIM + lane * 4)            = w1.u;
  *(ushort4*)(zn + (row + NPAIR) * DDIM + lane * 4)  = w2.u;

  if (lane == 0) pos_half[row] = s12 * i1 * i2 * BETA_INV;
}

// ---------------------------------------------------------------------------
// Kernel 2: symmetric Gram 256x256 tile + exp + row/col sums.
// Per-block cost was ~12.5K cy regardless of staging variant (r2/r5/r6) and
// co-residency is stuck at ~1.3 blocks/CU -> amortize: 4x the work per block.
// 528 blocks, 512 threads (8 waves as 2 row x 4 col), 1 block/CU.
// Per BK=64 chunk (verified r5/r6 schedule): DMA-stage A panel + B panel
// (each [256][64], 128B rows + self-inverse chunk XOR = the zero-conflict
// geometry) -> sync -> compute (8 rt x 4 ct x 2 ks MFMA from LDS) -> sync.
// Epilogue: mask only on the 32 diagonal tiles (gcol>grow, r3-verified);
// off-diagonal path branch-free. LDS cross-wave reduce -> 256 row atomics
// + 256 col atomics.
// ---------------------------------------------------------------------------
__global__ __launch_bounds__(512, 2) void cl_gram_expsum(
    const ushort* __restrict__ zn, float* __restrict__ denom) {
  // decode linear block id -> (i, j) with i <= j in the 32x32 upper triangle
  int idx = blockIdx.x;
  int j = (int)((sqrtf(8.0f * idx + 1.0f) - 1.0f) * 0.5f);
  while ((j + 1) * (j + 2) / 2 <= idx) ++j;
  while (j * (j + 1) / 2 > idx) --j;
  int i = idx - j * (j + 1) / 2;
  int brow = i * 256;
  int bcol = j * 256;
  bool diag = (i == j);

  __shared__ ushort As[256][64];    // 32 KiB A chunk, swizzled rows
  __shared__ ushort Bs[256][64];    // 32 KiB B chunk, swizzled rows

  int tid  = threadIdx.x;
  int wid  = tid >> 6;       // 0..7
  int lane = tid & 63;
  int l15  = lane & 15;
  int lg   = lane >> 4;
  int wr   = wid >> 2;       // 0..1: row half (128 rows)
  int wc   = wid & 3;        // 0..3: col quarter (64 cols)

  f32x4 acc[8][4];
  #pragma unroll
  for (int rt = 0; rt < 8; ++rt)
    #pragma unroll
    for (int ct = 0; ct < 4; ++ct)
      acc[rt][ct] = (f32x4){0.f, 0.f, 0.f, 0.f};

  int rlo = lane >> 3;            // 0..7: row within 1KB DMA chunk
  int s   = (lane & 7) ^ rlo;     // pre-swizzled source 16B-chunk index

  for (int kc = 0; kc < 4; ++kc) {
    // ---- stage A and B panels for this K-chunk: 8 DMAs per thread.
    // Each 16B DMA: wave writes 1 KiB linear = 8 rows x 128 B;
    // LDS(r, slot) holds global chunk slot ^ (r&7) (self-inverse swizzle).
    #pragma unroll
    for (int it = 0; it < 4; ++it) {
      int r0 = wid * 32 + it * 8;
      const ushort* srcA =
          zn + (size_t)(brow + r0 + rlo) * DDIM + kc * 64 + s * 8;
      __builtin_amdgcn_global_load_lds(
          (const __attribute__((address_space(1))) unsigned int*)srcA,
          (__attribute__((address_space(3))) unsigned int*)&As[r0][0],
          16, 0, 0);
      const ushort* srcB =
          zn + (size_t)(bcol + r0 + rlo) * DDIM + kc * 64 + s * 8;
      __builtin_amdgcn_global_load_lds(
          (const __attribute__((address_space(1))) unsigned int*)srcB,
          (__attribute__((address_space(3))) unsigned int*)&Bs[r0][0],
          16, 0, 0);
    }

    __syncthreads();   // vmcnt(0) drain: both panels resident

    // ---- compute chunk: per thread 24 ds_read_b128 + 64 MFMA
    #pragma unroll
    for (int ks = 0; ks < 2; ++ks) {
      int su = (4 * ks + lg) ^ (l15 & 7);   // swizzled 16B chunk on read
      bf16x8 af[8], bfv[4];
      #pragma unroll
      for (int rt = 0; rt < 8; ++rt)
        af[rt] = *(const bf16x8*)&As[128 * wr + 16 * rt + l15][su * 8];
      #pragma unroll
      for (int ct = 0; ct < 4; ++ct)
        bfv[ct] = *(const bf16x8*)&Bs[64 * wc + 16 * ct + l15][su * 8];
      #pragma unroll
      for (int rt = 0; rt < 8; ++rt)
        #pragma unroll
        for (int ct = 0; ct < 4; ++ct)
          acc[rt][ct] = __builtin_amdgcn_mfma_f32_16x16x32_bf16(
              af[rt], bfv[ct], acc[rt][ct], 0, 0, 0);
    }

    __syncthreads();   // all waves done reading panels before next stage
  }
  // (last sync above also makes As reusable for the reductions below)

  // ---- epilogue: e = exp(sim/beta); on diagonal tiles only contribute
  // iff gcol > grow (r3-verified uniform rule). Each e feeds a row sum
  // (this wave's 64-col slice) and a col sum.
  float* rowred = (float*)As;            // [4][256] floats = 4 KiB
  float* colred = ((float*)As) + 1024;   // [2][256] floats = 2 KiB

  float colacc[4] = {0.f, 0.f, 0.f, 0.f};

  #pragma unroll
  for (int rt = 0; rt < 8; ++rt) {
    int lrow = 128 * wr + 16 * rt + lg * 4;    // row within tile
    #pragma unroll
    for (int reg = 0; reg < 4; ++reg) {
      float rs = 0.f;
      if (diag) {
        int grow = brow + lrow + reg;
        #pragma unroll
        for (int ct = 0; ct < 4; ++ct) {
          int gcol = bcol + 64 * wc + 16 * ct + l15;
          float e = __expf(acc[rt][ct][reg] * BETA_INV);
          e = (gcol > grow) ? e : 0.f;
          rs += e;
          colacc[ct] += e;
        }
      } else {
        #pragma unroll
        for (int ct = 0; ct < 4; ++ct) {
          float e = __expf(acc[rt][ct][reg] * BETA_INV);
          rs += e;
          colacc[ct] += e;
        }
      }
      // reduce across the 16 cols held by this lg-group
      rs += __shfl_xor(rs, 1);
      rs += __shfl_xor(rs, 2);
      rs += __shfl_xor(rs, 4);
      rs += __shfl_xor(rs, 8);
      if (l15 == 0) rowred[wc * 256 + lrow + reg] = rs;
    }
  }

  // col sums: reduce across the 4 lg-groups (rows) within the wave
  #pragma unroll
  for (int ct = 0; ct < 4; ++ct) {
    float c = colacc[ct];
    c += __shfl_xor(c, 16);
    c += __shfl_xor(c, 32);
    if (lg == 0) colred[wr * 256 + 64 * wc + 16 * ct + l15] = c;
  }

  __syncthreads();

  // final: sum the per-wave layers, one atomic per row and per col
  if (tid < 256) {
    float r = rowred[tid] + rowred[256 + tid] + rowred[512 + tid] +
              rowred[768 + tid];
    atomicAdd(&denom[brow + tid], r);
  } else {
    int t = tid - 256;
    float c = colred[t] + colred[256 + t];
    atomicAdd(&denom[bcol + t], c);
  }
}

// ---------------------------------------------------------------------------
// Kernel 3: loss = (sum_i log(denom_i) - 2 * sum_i pos_half_i) / 8192
// ---------------------------------------------------------------------------
__global__ __launch_bounds__(1024) void cl_finalize(
    const float* __restrict__ denom, const float* __restrict__ pos_half,
    float* __restrict__ out) {
  float s = 0.f, p = 0.f;
  for (int i = threadIdx.x; i < MROWS; i += 1024) s += __logf(denom[i]);
  for (int i = threadIdx.x; i < NPAIR; i += 1024) p += pos_half[i];
  #pragma unroll
  for (int m = 1; m < 64; m <<= 1) {
    s += __shfl_xor(s, m);
    p += __shfl_xor(p, m);
  }
  __shared__ float red[2][16];
  int wid = threadIdx.x >> 6, lane = threadIdx.x & 63;
  if (lane == 0) { red[0][wid] = s; red[1][wid] = p; }
  __syncthreads();
  if (threadIdx.x == 0) {
    float S = 0.f, P = 0.f;
    #pragma unroll
    for (int w = 0; w < 16; ++w) { S += red[0][w]; P += red[1][w]; }
    out[0] = (S - 2.f * P) / (float)MROWS;
  }
}

extern "C" void kernel_launch(void* const* d_in, const int* in_sizes, int n_in,
                              void* d_out, int out_size, void* d_ws, size_t ws_size,
                              hipStream_t stream) {
  const float* x1 = (const float*)d_in[0];
  const float* x2 = (const float*)d_in[1];
  float* out = (float*)d_out;

  char* ws = (char*)d_ws;
  ushort* zn      = (ushort*)ws;                                 // 4 MiB bf16
  float*  denom   = (float*)(ws + (size_t)MROWS * DDIM * 2);     // 32 KiB
  float*  posh    = (float*)(ws + (size_t)MROWS * DDIM * 2 + MROWS * 4);

  cl_normalize<<<NPAIR / 4, 256, 0, stream>>>(x1, x2, zn, posh, denom);
  cl_gram_expsum<<<NBLK2, 512, 0, stream>>>(zn, denom);
  cl_finalize<<<1, 1024, 0, stream>>>(denom, posh, out);
}